// Round 12
// baseline (136.261 us; speedup 1.0000x reference)
//
#include <hip/hip_runtime.h>

#define HH 256
#define WW 256
#define NB 4
#define NC 128
#define HW (HH * WW)

// ---------- bf16 helpers (manual, RNE) ----------
__device__ __forceinline__ float blo(unsigned int u) { return __uint_as_float(u << 16); }
__device__ __forceinline__ float bhi(unsigned int u) { return __uint_as_float(u & 0xffff0000u); }
__device__ __forceinline__ unsigned int bf16_rne(float f) {
    unsigned int u = __float_as_uint(f);
    return (u + 0x7fffu + ((u >> 16) & 1u)) >> 16;  // finite inputs only
}
__device__ __forceinline__ unsigned int pack_bf16(float a, float b) {
    return bf16_rne(a) | (bf16_rne(b) << 16);
}
union U4 { uint4 v; unsigned int w[4]; };

// =====================================================================
// prep11: prep10 with FULL-ROW DMA runs (1KB vs 512B) — isolates the
// DRAM-run-length theory. Block = 2 rows x 256 cols x 64 channels.
// LDS: f32 [ch][256], 64KB, single buffer (2 blocks/CU overlap; occupancy
// proven null in r10/r11). DMA source pre-swizzled on 16B chunks
// (m173): lane l of channel ch fetches chunk l ^ ((ch>>2)&7); read back
// at lds[ch*256 + (px ^ 4e)]. Stores: 128B chunks, 1KB/wave (prep10's
// proven pattern). d1 fused via in-register accumulation (f32).
// =====================================================================
__global__ __launch_bounds__(256) void prep11_kernel(
        const float* __restrict__ feat1, const float* __restrict__ feat2,
        unsigned int* __restrict__ s0f1, unsigned int* __restrict__ s0f2,
        unsigned int* __restrict__ d1f1, unsigned int* __restrict__ d1f2) {
    __shared__ float lds[64 * 256];   // 64 KB

    int z = blockIdx.y;              // 0..15 : (feat, b, cg)
    int b = (z >> 1) & 3;
    int cg = z & 1;                  // channel group: 64*cg .. 64*cg+63
    const float* src = (z < 8 ? feat1 : feat2) + ((size_t)b * NC + 64 * cg) * HW;
    unsigned int* s0 = (z < 8 ? s0f1 : s0f2);
    unsigned int* d1 = (z < 8 ? d1f1 : d1f2);

    int y2 = blockIdx.x;        // 0..127 : rows 2*y2, 2*y2+1
    int tid = threadIdx.x;
    int w = tid >> 6;           // wave 0..3
    int l = tid & 63;

    // consume lane roles
    int c8 = l & 7;             // local channel chunk (8 ch)
    int m  = w * 8 + (l >> 3);  // 0..31 : pixel-pair slot
    int co = cg * 32 + c8 * 4;  // uint offset in HWC pixel vector

    float accLo[4][4], accHi[4][4];
#pragma unroll
    for (int i = 0; i < 4; ++i)
#pragma unroll
        for (int j = 0; j < 4; ++j) { accLo[i][j] = 0.0f; accHi[i][j] = 0.0f; }

#pragma unroll
    for (int phase = 0; phase < 2; ++phase) {
        int row = 2 * y2 + phase;
        // ---- DMA: wave w stages channels 16w..16w+15, 1KB run each ----
        {
            const float* rowbase = src + (size_t)row * WW;
#pragma unroll
            for (int k = 0; k < 16; ++k) {
                int ch = w * 16 + k;                 // local channel
                int e = (ch >> 2) & 7;               // 16B-chunk swizzle
                const float* g = rowbase + (size_t)ch * HW + 4 * (l ^ e);
                __builtin_amdgcn_global_load_lds(
                    (const __attribute__((address_space(1))) void*)g,
                    (__attribute__((address_space(3))) void*)&lds[ch * 256],
                    16, 0, 0);
            }
        }
        __syncthreads();

        // ---- consume: 4 pixel-pairs per thread; s0 stores + d1 accum ----
        size_t rowpix = ((size_t)(b * HH + row) * WW);
#pragma unroll
        for (int k = 0; k < 4; ++k) {
            int xd = k * 32 + m;                     // pair id / d1 col
            int px0 = 2 * xd;
            U4 u0, u1;
#pragma unroll
            for (int j = 0; j < 4; ++j) {
                int chA = 8 * c8 + 2 * j;
                int fe = 4 * ((chA >> 2) & 7);       // same for chA+1
                float a0 = lds[chA * 256 + (px0 ^ fe)];
                float a1 = lds[chA * 256 + ((px0 + 1) ^ fe)];
                float b0 = lds[(chA + 1) * 256 + (px0 ^ fe)];
                float b1 = lds[(chA + 1) * 256 + ((px0 + 1) ^ fe)];
                u0.w[j] = pack_bf16(a0, b0);
                u1.w[j] = pack_bf16(a1, b1);
                accLo[k][j] += a0 + a1;
                accHi[k][j] += b0 + b1;
            }
            *(uint4*)(s0 + (rowpix + px0) * 64 + co) = u0.v;
            *(uint4*)(s0 + (rowpix + px0 + 1) * 64 + co) = u1.v;
        }
        __syncthreads();   // reads done before next phase's DMA overwrites
    }

    // ---- emit d1 ----
    size_t d1row = (size_t)(b * 128 + y2) * 128;
#pragma unroll
    for (int k = 0; k < 4; ++k) {
        int xd = k * 32 + m;
        U4 o;
#pragma unroll
        for (int j = 0; j < 4; ++j)
            o.w[j] = pack_bf16(0.25f * accLo[k][j], 0.25f * accHi[k][j]);
        *(uint4*)(d1 + (d1row + xd) * 64 + co) = o.v;
    }
}

// =====================================================================
// ds_hwc<2>: HWC s0 -> HWC d2 (rows {4y+1,4y+2} x cols {4x+1,4x+2}).
// =====================================================================
template <int SC>
__global__ __launch_bounds__(256) void ds_hwc(
        const unsigned int* __restrict__ s0f1, const unsigned int* __restrict__ s0f2,
        unsigned int* __restrict__ df1, unsigned int* __restrict__ df2) {
    constexpr int S = (SC == 1) ? 128 : 64;
    int z = blockIdx.y;        // 0..7 : (feat, b)
    int b = z & 3;
    const unsigned int* s0 = (z < 4 ? s0f1 : s0f2) + ((size_t)b * HH * WW) * 64;
    unsigned int* d = (z < 4 ? df1 : df2) + ((size_t)b * S * S) * 64;

    int tid = blockIdx.x * 256 + threadIdx.x;
    int c8 = tid & 15;
    int p = tid >> 4;          // output pixel 0..S*S-1
    int yo = p / S, xo = p % S;
    int yi = (SC == 1) ? 2 * yo : 4 * yo + 1;
    int xi = (SC == 1) ? 2 * xo : 4 * xo + 1;

    const unsigned int* p00 = s0 + ((size_t)(yi * WW + xi)) * 64 + c8 * 4;
    U4 a, bb, c, dd, o;
    a.v  = *(const uint4*)p00;
    bb.v = *(const uint4*)(p00 + 64);
    c.v  = *(const uint4*)(p00 + WW * 64);
    dd.v = *(const uint4*)(p00 + WW * 64 + 64);
#pragma unroll
    for (int j = 0; j < 4; ++j) {
        float lo = blo(a.w[j]) + blo(bb.w[j]) + blo(c.w[j]) + blo(dd.w[j]);
        float hi = bhi(a.w[j]) + bhi(bb.w[j]) + bhi(c.w[j]) + bhi(dd.w[j]);
        o.w[j] = pack_bf16(0.25f * lo, 0.25f * hi);
    }
    *(uint4*)(d + (size_t)p * 64 + c8 * 4) = o.v;
}

// =====================================================================
// HWC corr: 16 lanes per pixel, one uint4 (8 bf16 ch) per lane.
// =====================================================================
template <int SCALE>
__global__ void corr_hwc(const unsigned int* __restrict__ f1,
                         const unsigned int* __restrict__ f2,
                         const float* __restrict__ offs,
                         float* __restrict__ out) {
    constexpr int S = (SCALE == 0) ? 256 : (SCALE == 1 ? 128 : 64);
    constexpr int LOGS = (SCALE == 0) ? 8 : (SCALE == 1 ? 7 : 6);
    int tid = threadIdx.x;
    int lane = tid & 15;
    int pix = blockIdx.x * 16 + (tid >> 4);
    int b = pix >> (2 * LOGS);
    int p = pix & (S * S - 1);
    int y = p >> LOGS;
    int x = p & (S - 1);

    const float* offx = offs + ((size_t)b * 6 + 2 * SCALE) * (HH * WW);
    const float* offy = offx + HH * WW;
    float dx, dy;
    if constexpr (SCALE == 0) {
        dx = offx[y * WW + x];
        dy = offy[y * WW + x];
    } else if constexpr (SCALE == 1) {
        const float* px = offx + (2 * y) * WW + 2 * x;
        const float* py = offy + (2 * y) * WW + 2 * x;
        dx = 0.125f * (px[0] + px[1] + px[WW] + px[WW + 1]);
        dy = 0.125f * (py[0] + py[1] + py[WW] + py[WW + 1]);
    } else {
        const float* px = offx + (4 * y + 1) * WW + 4 * x + 1;
        const float* py = offy + (4 * y + 1) * WW + 4 * x + 1;
        dx = 0.0625f * (px[0] + px[1] + px[WW] + px[WW + 1]);
        dy = 0.0625f * (py[0] + py[1] + py[WW] + py[WW + 1]);
    }

    float sx = (float)x + dx;
    float sy = (float)y + dy;
    float x0f = floorf(sx), y0f = floorf(sy);
    float wx1 = sx - x0f, wy1 = sy - y0f;
    float wx0 = 1.0f - wx1, wy0 = 1.0f - wy1;
    int x0 = (int)x0f, y0 = (int)y0f;
    int x1 = x0 + 1, y1 = y0 + 1;
    bool vx0 = (x0 >= 0) & (x0 < S);
    bool vx1 = (x1 >= 0) & (x1 < S);
    bool vy0 = (y0 >= 0) & (y0 < S);
    bool vy1 = (y1 >= 0) & (y1 < S);
    float w00 = wy0 * wx0 * (float)(vy0 & vx0);
    float w01 = wy0 * wx1 * (float)(vy0 & vx1);
    float w10 = wy1 * wx0 * (float)(vy1 & vx0);
    float w11 = wy1 * wx1 * (float)(vy1 & vx1);
    int cx0 = min(max(x0, 0), S - 1), cx1 = min(max(x1, 0), S - 1);
    int cy0 = min(max(y0, 0), S - 1), cy1 = min(max(y1, 0), S - 1);
    size_t pb = (size_t)b << (2 * LOGS);
    size_t i00 = pb + (cy0 << LOGS) + cx0, i01 = pb + (cy0 << LOGS) + cx1;
    size_t i10 = pb + (cy1 << LOGS) + cx0, i11 = pb + (cy1 << LOGS) + cx1;

    int lo = lane * 4;
    U4 a, c00, c01, c10, c11;
    a.v   = *(const uint4*)(f1 + ((size_t)pix << 6) + lo);
    c00.v = *(const uint4*)(f2 + (i00 << 6) + lo);
    c01.v = *(const uint4*)(f2 + (i01 << 6) + lo);
    c10.v = *(const uint4*)(f2 + (i10 << 6) + lo);
    c11.v = *(const uint4*)(f2 + (i11 << 6) + lo);

    float acc = 0.0f;
#pragma unroll
    for (int j = 0; j < 4; ++j) {
        float s_lo = w00 * blo(c00.w[j]) + w01 * blo(c01.w[j]) + w10 * blo(c10.w[j]) + w11 * blo(c11.w[j]);
        float s_hi = w00 * bhi(c00.w[j]) + w01 * bhi(c01.w[j]) + w10 * bhi(c10.w[j]) + w11 * bhi(c11.w[j]);
        acc = fmaf(blo(a.w[j]), s_lo, acc);
        acc = fmaf(bhi(a.w[j]), s_hi, acc);
    }
    acc += __shfl_xor(acc, 8);
    acc += __shfl_xor(acc, 4);
    acc += __shfl_xor(acc, 2);
    acc += __shfl_xor(acc, 1);

    if (lane == 0) {
        if constexpr (SCALE == 0) {
            out[((size_t)b * 3) * (HH * WW) + p] = acc;
        } else {
            out[(size_t)b * (S * S) + p] = acc;
        }
    }
}

// ---------------- upsample corr back to 256x256 ----------------
template <int SCALE>
__global__ void up_kernel(const float* __restrict__ corr, float* __restrict__ out) {
    constexpr int S = (SCALE == 1) ? 128 : 64;
    constexpr float R = (float)S / 256.0f;
    int idx = blockIdx.x * blockDim.x + threadIdx.x;
    if (idx >= NB * HH * WW) return;
    int x = idx & 255;
    int t = idx >> 8;
    int y = t & 255;
    int b = t >> 8;
    float srcx = fminf(fmaxf(((float)x + 0.5f) * R - 0.5f, 0.0f), (float)(S - 1));
    float srcy = fminf(fmaxf(((float)y + 0.5f) * R - 0.5f, 0.0f), (float)(S - 1));
    int x0 = (int)srcx;
    int y0 = (int)srcy;
    int x1 = min(x0 + 1, S - 1), y1 = min(y0 + 1, S - 1);
    float wx = srcx - (float)x0, wy = srcy - (float)y0;
    const float* cp = corr + (size_t)b * (S * S);
    float v0 = cp[y0 * S + x0] * (1.0f - wx) + cp[y0 * S + x1] * wx;
    float v1 = cp[y1 * S + x0] * (1.0f - wx) + cp[y1 * S + x1] * wx;
    out[((size_t)b * 3 + SCALE) * (HH * WW) + y * WW + x] = (1.0f - wy) * v0 + wy * v1;
}

extern "C" void kernel_launch(void* const* d_in, const int* in_sizes, int n_in,
                              void* d_out, int out_size, void* d_ws, size_t ws_size,
                              hipStream_t stream) {
    const float* feat1 = (const float*)d_in[0];
    const float* feat2 = (const float*)d_in[1];
    const float* offs  = (const float*)d_in[2];
    float* out = (float*)d_out;

    const size_t n_s0 = (size_t)NB * HH * WW * 64;
    const size_t n_d1 = (size_t)NB * 128 * 128 * 64;
    const size_t n_d2 = (size_t)NB * 64 * 64 * 64;
    const size_t n_c1 = (size_t)NB * 128 * 128;
    const size_t n_c2 = (size_t)NB * 64 * 64;
    const size_t need = (2 * (n_s0 + n_d1 + n_d2) + n_c1 + n_c2) * 4;
    if (ws_size < need) return;

    unsigned int* ws = (unsigned int*)d_ws;
    unsigned int* s0f1 = ws;
    unsigned int* s0f2 = s0f1 + n_s0;
    unsigned int* d1f1 = s0f2 + n_s0;
    unsigned int* d1f2 = d1f1 + n_d1;
    unsigned int* d2f1 = d1f2 + n_d1;
    unsigned int* d2f2 = d2f1 + n_d2;
    float* corr1 = (float*)(d2f2 + n_d2);
    float* corr2 = corr1 + n_c1;

    prep11_kernel<<<dim3(128, 16), 256, 0, stream>>>(feat1, feat2, s0f1, s0f2,
                                                     d1f1, d1f2);

    ds_hwc<2><<<dim3(256, 8), 256, 0, stream>>>(s0f1, s0f2, d2f1, d2f2);

    corr_hwc<0><<<NB * 65536 / 16, 256, 0, stream>>>(s0f1, s0f2, offs, out);
    corr_hwc<1><<<NB * 16384 / 16, 256, 0, stream>>>(d1f1, d1f2, offs, corr1);
    corr_hwc<2><<<NB * 4096 / 16, 256, 0, stream>>>(d2f1, d2f2, offs, corr2);

    up_kernel<1><<<(NB * HH * WW + 255) / 256, 256, 0, stream>>>(corr1, out);
    up_kernel<2><<<(NB * HH * WW + 255) / 256, 256, 0, stream>>>(corr2, out);
}

// Round 13
// 130.393 us; speedup vs baseline: 1.0450x; 1.0450x over previous
//
#include <hip/hip_runtime.h>

#define HH 256
#define WW 256
#define NB 4
#define NC 128
#define HW (HH * WW)

// ---------- bf16 helpers (manual, RNE) ----------
__device__ __forceinline__ float blo(unsigned int u) { return __uint_as_float(u << 16); }
__device__ __forceinline__ float bhi(unsigned int u) { return __uint_as_float(u & 0xffff0000u); }
__device__ __forceinline__ unsigned int bf16_rne(float f) {
    unsigned int u = __float_as_uint(f);
    return (u + 0x7fffu + ((u >> 16) & 1u)) >> 16;  // finite inputs only
}
__device__ __forceinline__ unsigned int pack_bf16(float a, float b) {
    return bf16_rne(a) | (bf16_rne(b) << 16);
}
union U4 { uint4 v; unsigned int w[4]; };

// =====================================================================
// prep9 (round-10 best): DMA staging + per-row consume over a ROW PAIR
// with fused d1 production. Measured 111 µs; best total (130.1 µs).
// LDS: f32 channel-major; DMA source pre-swizzled (m173 pattern).
// =====================================================================
__global__ __launch_bounds__(256) void prep9_kernel(
        const float* __restrict__ feat1, const float* __restrict__ feat2,
        unsigned int* __restrict__ s0f1, unsigned int* __restrict__ s0f2,
        unsigned int* __restrict__ d1f1, unsigned int* __restrict__ d1f2) {
    __shared__ float lds[128 * 128];   // 64 KB

    int z = blockIdx.z;
    int b = z & 3;
    const float* src = (z < 4 ? feat1 : feat2) + (size_t)b * NC * HW;
    unsigned int* s0 = (z < 4 ? s0f1 : s0f2);
    unsigned int* d1 = (z < 4 ? d1f1 : d1f2);

    int y2 = blockIdx.y;        // 0..127 : rows 2*y2, 2*y2+1
    int bx = blockIdx.x;        // 0..1   : 128-col half
    int tid = threadIdx.x;
    int w = tid >> 6;           // wave 0..3
    int l = tid & 63;

    // DMA lane roles
    int half = l >> 5;          // 0: even channel of pair, 1: odd
    int cc = l & 31;            // 16B col-chunk id
    // consume lane roles
    int c8 = l & 15;            // channel chunk (8 ch)
    int pr = l >> 4;            // 0..3 pair slot
    int e = c8 & 7;

    float accLo[4][4], accHi[4][4];
#pragma unroll
    for (int i = 0; i < 4; ++i)
#pragma unroll
        for (int j = 0; j < 4; ++j) { accLo[i][j] = 0.0f; accHi[i][j] = 0.0f; }

#pragma unroll
    for (int phase = 0; phase < 2; ++phase) {
        int row = 2 * y2 + phase;
        // ---- DMA: wave w stages channel pairs 16w..16w+15 (16 x 1KB) ----
        {
            const float* rowbase = src + (size_t)row * WW + bx * 128;
#pragma unroll
            for (int k = 0; k < 16; ++k) {
                int cp = w * 16 + k;
                int ed = (cp >> 2) & 7;
                int ch = 2 * cp + half;
                const float* g = rowbase + (size_t)ch * HW + 4 * (cc ^ ed);
                __builtin_amdgcn_global_load_lds(
                    (const __attribute__((address_space(1))) void*)g,
                    (__attribute__((address_space(3))) void*)&lds[cp * 256],
                    16, 0, 0);
            }
        }
        __syncthreads();

        // ---- consume: 4 items -> pixel pairs, s0 stores + d1 accum ----
        size_t rowpix = ((size_t)(b * HH + row) * WW + bx * 128);
#pragma unroll
        for (int it = 0; it < 4; ++it) {
            int m = it * 16 + w * 4 + pr;          // pair id 0..63
            int col0 = 4 * ((m >> 1) ^ e) + 2 * (m & 1);
            U4 u0, u1;
#pragma unroll
            for (int j = 0; j < 4; ++j) {
                int ch = 8 * c8 + 2 * j;
                float lo0 = lds[ch * 128 + col0];
                float lo1 = lds[ch * 128 + col0 + 1];
                float hi0 = lds[(ch + 1) * 128 + col0];
                float hi1 = lds[(ch + 1) * 128 + col0 + 1];
                u0.w[j] = pack_bf16(lo0, hi0);
                u1.w[j] = pack_bf16(lo1, hi1);
                accLo[it][j] += lo0 + lo1;
                accHi[it][j] += hi0 + hi1;
            }
            *(uint4*)(s0 + (rowpix + 2 * m) * 64 + c8 * 4) = u0.v;
            *(uint4*)(s0 + (rowpix + 2 * m + 1) * 64 + c8 * 4) = u1.v;
        }
        __syncthreads();   // all reads done before next phase's DMA overwrites
    }

    // ---- emit d1: 1KB contiguous per wave per it ----
    size_t d1row = ((size_t)(b * 128 + y2) * 128 + bx * 64);
#pragma unroll
    for (int it = 0; it < 4; ++it) {
        int m = it * 16 + w * 4 + pr;
        U4 o;
#pragma unroll
        for (int j = 0; j < 4; ++j)
            o.w[j] = pack_bf16(0.25f * accLo[it][j], 0.25f * accHi[it][j]);
        *(uint4*)(d1 + (d1row + m) * 64 + c8 * 4) = o.v;
    }
}

// =====================================================================
// ds_hwc<2>: HWC s0 -> HWC d2 (rows {4y+1,4y+2} x cols {4x+1,4x+2}).
// =====================================================================
template <int SC>
__global__ __launch_bounds__(256) void ds_hwc(
        const unsigned int* __restrict__ s0f1, const unsigned int* __restrict__ s0f2,
        unsigned int* __restrict__ df1, unsigned int* __restrict__ df2) {
    constexpr int S = (SC == 1) ? 128 : 64;
    int z = blockIdx.y;        // 0..7 : (feat, b)
    int b = z & 3;
    const unsigned int* s0 = (z < 4 ? s0f1 : s0f2) + ((size_t)b * HH * WW) * 64;
    unsigned int* d = (z < 4 ? df1 : df2) + ((size_t)b * S * S) * 64;

    int tid = blockIdx.x * 256 + threadIdx.x;
    int c8 = tid & 15;
    int p = tid >> 4;          // output pixel 0..S*S-1
    int yo = p / S, xo = p % S;
    int yi = (SC == 1) ? 2 * yo : 4 * yo + 1;
    int xi = (SC == 1) ? 2 * xo : 4 * xo + 1;

    const unsigned int* p00 = s0 + ((size_t)(yi * WW + xi)) * 64 + c8 * 4;
    U4 a, bb, c, dd, o;
    a.v  = *(const uint4*)p00;
    bb.v = *(const uint4*)(p00 + 64);
    c.v  = *(const uint4*)(p00 + WW * 64);
    dd.v = *(const uint4*)(p00 + WW * 64 + 64);
#pragma unroll
    for (int j = 0; j < 4; ++j) {
        float lo = blo(a.w[j]) + blo(bb.w[j]) + blo(c.w[j]) + blo(dd.w[j]);
        float hi = bhi(a.w[j]) + bhi(bb.w[j]) + bhi(c.w[j]) + bhi(dd.w[j]);
        o.w[j] = pack_bf16(0.25f * lo, 0.25f * hi);
    }
    *(uint4*)(d + (size_t)p * 64 + c8 * 4) = o.v;
}

// =====================================================================
// HWC corr: 16 lanes per pixel, one uint4 (8 bf16 ch) per lane.
// =====================================================================
template <int SCALE>
__global__ void corr_hwc(const unsigned int* __restrict__ f1,
                         const unsigned int* __restrict__ f2,
                         const float* __restrict__ offs,
                         float* __restrict__ out) {
    constexpr int S = (SCALE == 0) ? 256 : (SCALE == 1 ? 128 : 64);
    constexpr int LOGS = (SCALE == 0) ? 8 : (SCALE == 1 ? 7 : 6);
    int tid = threadIdx.x;
    int lane = tid & 15;
    int pix = blockIdx.x * 16 + (tid >> 4);
    int b = pix >> (2 * LOGS);
    int p = pix & (S * S - 1);
    int y = p >> LOGS;
    int x = p & (S - 1);

    const float* offx = offs + ((size_t)b * 6 + 2 * SCALE) * (HH * WW);
    const float* offy = offx + HH * WW;
    float dx, dy;
    if constexpr (SCALE == 0) {
        dx = offx[y * WW + x];
        dy = offy[y * WW + x];
    } else if constexpr (SCALE == 1) {
        const float* px = offx + (2 * y) * WW + 2 * x;
        const float* py = offy + (2 * y) * WW + 2 * x;
        dx = 0.125f * (px[0] + px[1] + px[WW] + px[WW + 1]);
        dy = 0.125f * (py[0] + py[1] + py[WW] + py[WW + 1]);
    } else {
        const float* px = offx + (4 * y + 1) * WW + 4 * x + 1;
        const float* py = offy + (4 * y + 1) * WW + 4 * x + 1;
        dx = 0.0625f * (px[0] + px[1] + px[WW] + px[WW + 1]);
        dy = 0.0625f * (py[0] + py[1] + py[WW] + py[WW + 1]);
    }

    float sx = (float)x + dx;
    float sy = (float)y + dy;
    float x0f = floorf(sx), y0f = floorf(sy);
    float wx1 = sx - x0f, wy1 = sy - y0f;
    float wx0 = 1.0f - wx1, wy0 = 1.0f - wy1;
    int x0 = (int)x0f, y0 = (int)y0f;
    int x1 = x0 + 1, y1 = y0 + 1;
    bool vx0 = (x0 >= 0) & (x0 < S);
    bool vx1 = (x1 >= 0) & (x1 < S);
    bool vy0 = (y0 >= 0) & (y0 < S);
    bool vy1 = (y1 >= 0) & (y1 < S);
    float w00 = wy0 * wx0 * (float)(vy0 & vx0);
    float w01 = wy0 * wx1 * (float)(vy0 & vx1);
    float w10 = wy1 * wx0 * (float)(vy1 & vx0);
    float w11 = wy1 * wx1 * (float)(vy1 & vx1);
    int cx0 = min(max(x0, 0), S - 1), cx1 = min(max(x1, 0), S - 1);
    int cy0 = min(max(y0, 0), S - 1), cy1 = min(max(y1, 0), S - 1);
    size_t pb = (size_t)b << (2 * LOGS);
    size_t i00 = pb + (cy0 << LOGS) + cx0, i01 = pb + (cy0 << LOGS) + cx1;
    size_t i10 = pb + (cy1 << LOGS) + cx0, i11 = pb + (cy1 << LOGS) + cx1;

    int lo = lane * 4;
    U4 a, c00, c01, c10, c11;
    a.v   = *(const uint4*)(f1 + ((size_t)pix << 6) + lo);
    c00.v = *(const uint4*)(f2 + (i00 << 6) + lo);
    c01.v = *(const uint4*)(f2 + (i01 << 6) + lo);
    c10.v = *(const uint4*)(f2 + (i10 << 6) + lo);
    c11.v = *(const uint4*)(f2 + (i11 << 6) + lo);

    float acc = 0.0f;
#pragma unroll
    for (int j = 0; j < 4; ++j) {
        float s_lo = w00 * blo(c00.w[j]) + w01 * blo(c01.w[j]) + w10 * blo(c10.w[j]) + w11 * blo(c11.w[j]);
        float s_hi = w00 * bhi(c00.w[j]) + w01 * bhi(c01.w[j]) + w10 * bhi(c10.w[j]) + w11 * bhi(c11.w[j]);
        acc = fmaf(blo(a.w[j]), s_lo, acc);
        acc = fmaf(bhi(a.w[j]), s_hi, acc);
    }
    acc += __shfl_xor(acc, 8);
    acc += __shfl_xor(acc, 4);
    acc += __shfl_xor(acc, 2);
    acc += __shfl_xor(acc, 1);

    if (lane == 0) {
        if constexpr (SCALE == 0) {
            out[((size_t)b * 3) * (HH * WW) + p] = acc;
        } else {
            out[(size_t)b * (S * S) + p] = acc;
        }
    }
}

// ---------------- upsample corr back to 256x256 ----------------
template <int SCALE>
__global__ void up_kernel(const float* __restrict__ corr, float* __restrict__ out) {
    constexpr int S = (SCALE == 1) ? 128 : 64;
    constexpr float R = (float)S / 256.0f;
    int idx = blockIdx.x * blockDim.x + threadIdx.x;
    if (idx >= NB * HH * WW) return;
    int x = idx & 255;
    int t = idx >> 8;
    int y = t & 255;
    int b = t >> 8;
    float srcx = fminf(fmaxf(((float)x + 0.5f) * R - 0.5f, 0.0f), (float)(S - 1));
    float srcy = fminf(fmaxf(((float)y + 0.5f) * R - 0.5f, 0.0f), (float)(S - 1));
    int x0 = (int)srcx;
    int y0 = (int)srcy;
    int x1 = min(x0 + 1, S - 1), y1 = min(y0 + 1, S - 1);
    float wx = srcx - (float)x0, wy = srcy - (float)y0;
    const float* cp = corr + (size_t)b * (S * S);
    float v0 = cp[y0 * S + x0] * (1.0f - wx) + cp[y0 * S + x1] * wx;
    float v1 = cp[y1 * S + x0] * (1.0f - wx) + cp[y1 * S + x1] * wx;
    out[((size_t)b * 3 + SCALE) * (HH * WW) + y * WW + x] = (1.0f - wy) * v0 + wy * v1;
}

extern "C" void kernel_launch(void* const* d_in, const int* in_sizes, int n_in,
                              void* d_out, int out_size, void* d_ws, size_t ws_size,
                              hipStream_t stream) {
    const float* feat1 = (const float*)d_in[0];
    const float* feat2 = (const float*)d_in[1];
    const float* offs  = (const float*)d_in[2];
    float* out = (float*)d_out;

    const size_t n_s0 = (size_t)NB * HH * WW * 64;
    const size_t n_d1 = (size_t)NB * 128 * 128 * 64;
    const size_t n_d2 = (size_t)NB * 64 * 64 * 64;
    const size_t n_c1 = (size_t)NB * 128 * 128;
    const size_t n_c2 = (size_t)NB * 64 * 64;
    const size_t need = (2 * (n_s0 + n_d1 + n_d2) + n_c1 + n_c2) * 4;
    if (ws_size < need) return;

    unsigned int* ws = (unsigned int*)d_ws;
    unsigned int* s0f1 = ws;
    unsigned int* s0f2 = s0f1 + n_s0;
    unsigned int* d1f1 = s0f2 + n_s0;
    unsigned int* d1f2 = d1f1 + n_d1;
    unsigned int* d2f1 = d1f2 + n_d1;
    unsigned int* d2f2 = d2f1 + n_d2;
    float* corr1 = (float*)(d2f2 + n_d2);
    float* corr2 = corr1 + n_c1;

    prep9_kernel<<<dim3(2, 128, 8), 256, 0, stream>>>(feat1, feat2, s0f1, s0f2,
                                                      d1f1, d1f2);

    ds_hwc<2><<<dim3(256, 8), 256, 0, stream>>>(s0f1, s0f2, d2f1, d2f2);

    corr_hwc<0><<<NB * 65536 / 16, 256, 0, stream>>>(s0f1, s0f2, offs, out);
    corr_hwc<1><<<NB * 16384 / 16, 256, 0, stream>>>(d1f1, d1f2, offs, corr1);
    corr_hwc<2><<<NB * 4096 / 16, 256, 0, stream>>>(d2f1, d2f2, offs, corr2);

    up_kernel<1><<<(NB * HH * WW + 255) / 256, 256, 0, stream>>>(corr1, out);
    up_kernel<2><<<(NB * HH * WW + 255) / 256, 256, 0, stream>>>(corr2, out);
}